// Round 2
// baseline (1994.023 us; speedup 1.0000x reference)
//
#include <hip/hip_runtime.h>
#include <hip/hip_bf16.h>

// SNN: B=256, IN=1024, HID=2048, OUT=10, T=100, decay=0.9, thr=1.0, reset=0.
// Layer-pipelined: GEMM1(all t) -> LIF scan -> GEMM2(all t) -> scan -> GEMM3 -> scan.
// Hidden GEMMs: i8 Ozaki split, 4 digit planes of round(w*2^31) (exact split;
// i32 MFMA accumulation exact).
// Round-16 structure (vs r15):
//  - gemm_i8: wave = 64 rows x 16 cols (block 256x16, 4 waves). Each B fragment
//    (ds_read_b128) now feeds 4 MFMAs (4 row-groups) instead of 2 -> LDS read
//    traffic per MFMA-op HALVED (r15 was LDS-BW co-limited: 160KB/CU/iter ~
//    1430cyc vs 1306cyc matrix). acc [4][4] v4i = 64 regs unchanged; mask ring
//    2-slot x 4 groups = 16 regs (was 32) -> still (256,4) occupancy.
//    Per iter per wave: 1 global_load_lds (1KB plane) + 4 mask loads = 5 VMEM;
//    "s_waitcnt vmcnt(10); s_barrier" keeps 2 iters in flight; 4-deep LDS ring.
//  - cvt_w_i8: regions now 4KB per (16-col strip, w-group), plane c at c*1024.
//  - lif_scan / lif_out: 4-deep load prefetch (were serial ~900cyc/step
//    dependent-latency chains).
//  - C currents fp32 (exact i32 -> fp32), CH=100 single chunk.

#define B 256
#define IN_DIM 1024
#define HID 2048
#define OUT_DIM 10
#define T_STEPS 100
#define NCH 4
#define RT (T_STEPS * B)   // 25600 global rows

typedef unsigned long long ull;
typedef int v4i __attribute__((ext_vector_type(4)));

// ---- weight fp32 -> 4 signed base-256 digit planes of round(w*2^31),
// swizzled to MFMA fragment order: region per (nb16, wb) = 4096 B, plane c at
// c*1024, byte lane*16+jj, lane=lk*16+li, col = nb16*16 + li,
// k = wb*64 + lk*16 + jj.  One thread: 4 consecutive k (same n). ----
template<int K>
__global__ __launch_bounds__(256) void cvt_w_i8(
    const float* __restrict__ W, signed char* __restrict__ Bq)
{
    constexpr int WPR = K / 64;
    size_t id = (size_t)blockIdx.x * 256 + threadIdx.x;
    if (id >= (size_t)(K / 4) * HID) return;
    int n  = (int)(id % HID);
    int kg = (int)(id / HID);
    int k0 = kg * 4;                                  // jj multiple of 4
    signed char dig[4][4];                            // [plane][i]
#pragma unroll
    for (int i = 0; i < 4; ++i) {
        double w = (double)W[(size_t)(k0 + i) * HID + n];
        long long V = __double2ll_rn(w * 2147483648.0);   // w * 2^31
#pragma unroll
        for (int c = 0; c < 3; ++c) {
            int r = (int)(signed char)(V & 0xFF);     // balanced digit [-128,127]
            dig[c][i] = (signed char)r;
            V = (V - r) >> 8;
        }
        dig[3][i] = (signed char)V;                   // |V| <= ~70
    }
    int wb = k0 >> 6, lk = (k0 >> 4) & 3, jj = k0 & 15;
    int nb16 = n >> 4, li = n & 15;
    int lane = lk * 16 + li;
    size_t base = ((size_t)nb16 * WPR + wb) * 4096 + (size_t)lane * 16 + jj;
#pragma unroll
    for (int c = 0; c < 4; ++c) {
        unsigned pk = (unsigned)(unsigned char)dig[c][0]
                    | ((unsigned)(unsigned char)dig[c][1] << 8)
                    | ((unsigned)(unsigned char)dig[c][2] << 16)
                    | ((unsigned)(unsigned char)dig[c][3] << 24);
        *reinterpret_cast<unsigned*>(Bq + base + (size_t)c * 1024) = pk;
    }
}

// ---- output weights fp32 -> fp64 (gemm_out stays fp64) ----
__global__ __launch_bounds__(256) void cvt_who(
    const float* __restrict__ who, double* __restrict__ Who64)
{
    int i = blockIdx.x * 256 + threadIdx.x;
    if (i < HID * OUT_DIM) Who64[i] = (double)who[i];
}

// ---- bit-pack input spikes -> TRANSPOSED XbitsT[w][t*256+b] ----
__global__ __launch_bounds__(256) void bitpack_input(
    const float* __restrict__ inp, ull* __restrict__ XbitsT)
{
    int g = blockIdx.x * 4 + (threadIdx.x >> 6);
    int lane = threadIdx.x & 63;
    int b = g >> 4;
    int ig = g & 15;
    int i = ig * 64 + lane;
    const float4* p = (const float4*)(inp + ((size_t)b * IN_DIM + i) * T_STEPS);
    ull* dst = XbitsT + (size_t)ig * RT + b;
#pragma unroll 1
    for (int t4 = 0; t4 < T_STEPS / 4; ++t4) {
        float4 v = p[t4];
        ull m0 = __ballot(v.x > 0.5f);
        ull m1 = __ballot(v.y > 0.5f);
        ull m2 = __ballot(v.z > 0.5f);
        ull m3 = __ballot(v.w > 0.5f);
        if (lane == 0) {
            dst[(size_t)(t4 * 4 + 0) * B] = m0;
            dst[(size_t)(t4 * 4 + 1) * B] = m1;
            dst[(size_t)(t4 * 4 + 2) * B] = m2;
            dst[(size_t)(t4 * 4 + 3) * B] = m3;
        }
    }
}

// ---- i8 Ozaki bit-GEMM: 64 rows x 16 cols per wave ----
// Block: 256 rows x 16 cols, 4 waves. Grid: x = rows/256, y = HID/16.
// Per iter per wave: 4 ds_read_b128 feed 16 MFMA (4 row-groups share each B
// fragment). 1 stage (1KB plane) + 4 mask loads = 5 VMEM/iter uniform.
template<int K>
__global__ __launch_bounds__(256, 4) void gemm_i8(
    const ull* __restrict__ bitsT, int row_base,
    const signed char* __restrict__ Bq, float* __restrict__ C)
{
    constexpr int WPR = K / 64;
    __shared__ __align__(16) signed char blds[4][4096];   // 16 KB

    const int tid = threadIdx.x;
    const int lane = tid & 63;
    const int wv = __builtin_amdgcn_readfirstlane(tid >> 6);
    const int row0 = blockIdx.x * 256;                    // local row base
    const int c0 = blockIdx.y * 16;
    const int li = lane & 15;
    const int lk = lane >> 4;
    const int sh = lk * 16;
    const int r0l = wv * 64;

    const signed char* __restrict__ bsrc = Bq + (size_t)blockIdx.y * WPR * 4096;
    // lane li holds the mask of row (row0 + wv*64 + g*16 + li); replicated x4 over lk.
    const ull* __restrict__ mp = bitsT + (row_base + row0 + r0l + li);

    // stage B(w) plane wv into blds[bb][wv*1024 ..] (async to LDS, 1KB/wave)
    auto stage_b = [&](int w, int bb) {
        const signed char* src = bsrc + (size_t)w * 4096 + wv * 1024 + lane * 16;
        __builtin_amdgcn_global_load_lds(
            (const __attribute__((address_space(1))) unsigned int*)src,
            (__attribute__((address_space(3))) unsigned int*)(&blds[bb][wv * 1024 + lane * 16]),
            16, 0, 0);
    };

    // prologue: B(0..2) -> buf0..2; masks for w=0,1 into 2-slot ring
    stage_b(0, 0);
    stage_b(1, 1);
    stage_b(2, 2);
    ull r[2][4];
#pragma unroll
    for (int g = 0; g < 4; ++g) {
        r[0][g] = mp[(size_t)0 * RT + g * 16];
        r[1][g] = mp[(size_t)1 * RT + g * 16];
    }
    __syncthreads();

    v4i acc[4][NCH];   // [row-group][plane]
#pragma unroll
    for (int g = 0; g < 4; ++g)
#pragma unroll
        for (int c = 0; c < NCH; ++c) acc[g][c] = (v4i){0, 0, 0, 0};

    // main loop: iter w reads blds[w&3] + mask slot (w&1); stages w+3 into
    // slot (w+3)&3, refills mask slot with w+2. Hand-unrolled x4: all ring
    // indices compile-time (WPR % 4 == 0).
#pragma unroll 1
    for (int wb4 = 0; wb4 < WPR; wb4 += 4) {
#pragma unroll
        for (int u = 0; u < 4; ++u) {
            const int w = wb4 + u;
            int wn = w + 3;
            if (wn >= WPR) wn -= WPR;      // tail: dummy-but-valid, never consumed
            int wm = w + 2;
            if (wm >= WPR) wm -= WPR;
            stage_b(wn, (u + 3) & 3);

            ull m[4];
#pragma unroll
            for (int g = 0; g < 4; ++g) {
                m[g] = r[u & 1][g];
                r[u & 1][g] = mp[(size_t)wm * RT + g * 16];
            }

            // A fragments from masks (bit -> byte via mul-spread)
            v4i a[4];
#pragma unroll
            for (int g = 0; g < 4; ++g) {
                unsigned s = (unsigned)(m[g] >> sh) & 0xFFFFu;
#pragma unroll
                for (int d = 0; d < 4; ++d)
                    a[g][d] = (int)((((s >> (4 * d)) & 0xFu) * 0x00204081u) & 0x01010101u);
            }

#pragma unroll
            for (int c = 0; c < NCH; ++c) {
                v4i b = *(const v4i*)(&blds[u][c * 1024 + lane * 16]);
#pragma unroll
                for (int g = 0; g < 4; ++g)
                    acc[g][c] = __builtin_amdgcn_mfma_i32_16x16x64_i8(a[g], b, acc[g][c], 0, 0, 0);
            }

            // drain only iter (w-2)'s 5 loads; last 2 iters (10) stay in flight
            __asm__ __volatile__("s_waitcnt vmcnt(10)\n\ts_barrier" ::: "memory");
        }
    }

    // exact recombination: V = (((S3<<8)+S2)<<8+S1)<<8+S0; |V| < 2^43.
#pragma unroll
    for (int g = 0; g < 4; ++g) {
#pragma unroll
        for (int rr = 0; rr < 4; ++rr) {
            long long V = (long long)acc[g][3][rr];
            V = (V << 8) + (long long)acc[g][2][rr];
            V = (V << 8) + (long long)acc[g][1][rr];
            V = (V << 8) + (long long)acc[g][0][rr];
            C[(size_t)(row0 + r0l + g * 16 + lk * 4 + rr) * HID + c0 + li] =
                (float)((double)V * 0x1p-31);
        }
    }
}

// ---- output bit-GEMM: 10 columns, fp64; 4-way k-split + LDS reduce ----
__global__ __launch_bounds__(256) void gemm_out(
    const ull* __restrict__ bitsT, int row_base,
    const double* __restrict__ W, double* __restrict__ C3)
{
    __shared__ double part[3][64][OUT_DIM];   // 15.4 KB
    const int lane = threadIdx.x & 63;
    const int sl = threadIdx.x >> 6;          // k-slice 0..3
    const int row = blockIdx.x * 64 + lane;

    double acc[OUT_DIM];
#pragma unroll
    for (int j = 0; j < OUT_DIM; ++j) acc[j] = 0.0;

    for (int w = sl * 8; w < sl * 8 + 8; ++w) {
        ull m = bitsT[(size_t)w * RT + row_base + row];
        const double* __restrict__ wk = W + (size_t)(w * 64) * OUT_DIM;
#pragma unroll 4
        for (int kk = 0; kk < 64; ++kk) {
            double bd = (double)(unsigned int)(m & 1ull);
            m >>= 1;
#pragma unroll
            for (int j = 0; j < OUT_DIM; ++j)
                acc[j] = fma(bd, wk[j], acc[j]);
            wk += OUT_DIM;
        }
    }
    if (sl) {
#pragma unroll
        for (int j = 0; j < OUT_DIM; ++j) part[sl - 1][lane][j] = acc[j];
    }
    __syncthreads();
    if (sl == 0) {
        double* __restrict__ crow = C3 + (size_t)row * OUT_DIM;
#pragma unroll
        for (int j = 0; j < OUT_DIM; ++j)
            crow[j] = acc[j] + part[0][lane][j] + part[1][lane][j] + part[2][lane][j];
    }
}

// ---- LIF scan for a hidden layer; 4-deep load prefetch ----
__global__ __launch_bounds__(256) void lif_scan(
    const float* __restrict__ C, double* __restrict__ vstate,
    ull* __restrict__ SbitsT, int row_base, int Tl, int first)
{
    int g = blockIdx.x * 4 + (threadIdx.x >> 6);
    int lane = threadIdx.x & 63;
    int b = g >> 5;
    int ng = g & 31;
    int n = ng * 64 + lane;
    const float* __restrict__ Cp = C + (size_t)b * HID + n;
    ull* __restrict__ Sp = SbitsT + (size_t)ng * RT + row_base + b;
    double v = first ? 0.0 : vstate[(size_t)b * HID + n];
    int tl = 0;
    for (; tl + 4 <= Tl; tl += 4) {
        float c0 = Cp[(size_t)(tl + 0) * (B * HID)];
        float c1 = Cp[(size_t)(tl + 1) * (B * HID)];
        float c2 = Cp[(size_t)(tl + 2) * (B * HID)];
        float c3 = Cp[(size_t)(tl + 3) * (B * HID)];
#pragma unroll
        for (int i = 0; i < 4; ++i) {
            float cc = (i == 0) ? c0 : (i == 1) ? c1 : (i == 2) ? c2 : c3;
            v = v * 0.9 + (double)cc;
            bool s = (v >= 1.0);
            if (s) v = 0.0;
            ull mask = __ballot(s);
            if (lane == 0) Sp[(size_t)(tl + i) * B] = mask;
        }
    }
    for (; tl < Tl; ++tl) {
        double c = (double)Cp[(size_t)tl * (B * HID)];
        v = v * 0.9 + c;
        bool s = (v >= 1.0);
        if (s) v = 0.0;
        ull mask = __ballot(s);
        if (lane == 0) Sp[(size_t)tl * B] = mask;
    }
    vstate[(size_t)b * HID + n] = v;
}

// ---- output LIF scan + rate accumulation; 4-deep prefetch ----
__global__ __launch_bounds__(256) void lif_out(
    const double* __restrict__ C3, double* __restrict__ vstate,
    int* __restrict__ cnt_state, float* __restrict__ out, int Tl, int first)
{
    int tid = blockIdx.x * 256 + threadIdx.x;
    if (tid >= B * OUT_DIM) return;
    int b = tid / OUT_DIM, o = tid % OUT_DIM;
    const double* __restrict__ Cp = C3 + (size_t)b * OUT_DIM + o;
    double v = first ? 0.0 : vstate[tid];
    int cnt = first ? 0 : cnt_state[tid];
    int tl = 0;
    for (; tl + 4 <= Tl; tl += 4) {
        double c0 = Cp[(size_t)(tl + 0) * (B * OUT_DIM)];
        double c1 = Cp[(size_t)(tl + 1) * (B * OUT_DIM)];
        double c2 = Cp[(size_t)(tl + 2) * (B * OUT_DIM)];
        double c3 = Cp[(size_t)(tl + 3) * (B * OUT_DIM)];
#pragma unroll
        for (int i = 0; i < 4; ++i) {
            double cc = (i == 0) ? c0 : (i == 1) ? c1 : (i == 2) ? c2 : c3;
            v = v * 0.9 + cc;
            if (v >= 1.0) { cnt++; v = 0.0; }
        }
    }
    for (; tl < Tl; ++tl) {
        double c = Cp[(size_t)tl * (B * OUT_DIM)];
        v = v * 0.9 + c;
        if (v >= 1.0) { cnt++; v = 0.0; }
    }
    vstate[tid] = v;
    cnt_state[tid] = cnt;
    out[tid] = (float)((double)cnt / (double)T_STEPS);
}

extern "C" void kernel_launch(void* const* d_in, const int* in_sizes, int n_in,
                              void* d_out, int out_size, void* d_ws, size_t ws_size,
                              hipStream_t stream) {
    const float* inp = (const float*)d_in[0];   // [256,1024,100]
    const float* wih = (const float*)d_in[1];   // [1024,2048]
    const float* whh = (const float*)d_in[2];   // [1,2048,2048]
    const float* who = (const float*)d_in[3];   // [2048,10]
    float* out = (float*)d_out;                 // [256,10]

    // ---- workspace layout ----
    unsigned char* p = (unsigned char*)d_ws;
    auto alloc = [&](size_t sz) -> void* {
        void* r = (void*)p;
        p += (sz + 255) & ~(size_t)255;
        return r;
    };
    signed char* Bq1 = (signed char*)alloc((size_t)NCH * HID * IN_DIM + 4096); // 8.4 MB
    signed char* Bq2 = (signed char*)alloc((size_t)NCH * HID * HID + 4096);    // 16.8 MB
    double* Who64 = (double*)alloc((size_t)HID * OUT_DIM * 8);
    ull* XbitsT = (ull*)alloc((size_t)16 * RT * 8);        // 3.3 MB
    ull* S1T    = (ull*)alloc((size_t)32 * RT * 8);        // 6.6 MB
    ull* S2T    = (ull*)alloc((size_t)32 * RT * 8);        // 6.6 MB
    double* v1 = (double*)alloc((size_t)B * HID * 8);
    double* v2 = (double*)alloc((size_t)B * HID * 8);
    double* vo = (double*)alloc((size_t)B * OUT_DIM * 8);
    int* cnts  = (int*)alloc((size_t)B * OUT_DIM * 4);

    size_t used = (size_t)(p - (unsigned char*)d_ws);
    size_t remain = (ws_size > used) ? (ws_size - used) : 0;
    size_t per_t = (size_t)B * HID * 4 + (size_t)B * OUT_DIM * 8 + 1024;
    int CH = (int)(remain / per_t);
    if (CH > T_STEPS) CH = T_STEPS;
    if (CH < 1) CH = 1;
    double* C3 = (double*)alloc((size_t)CH * B * OUT_DIM * 8);
    float* C   = (float*)alloc((size_t)CH * B * HID * 4);

    // ---- one-time prep ----
    cvt_w_i8<IN_DIM><<<((IN_DIM / 4) * HID + 255) / 256, 256, 0, stream>>>(wih, Bq1);
    cvt_w_i8<HID><<<((HID / 4) * HID + 255) / 256, 256, 0, stream>>>(whh, Bq2);
    cvt_who<<<(HID * OUT_DIM + 255) / 256, 256, 0, stream>>>(who, Who64);
    bitpack_input<<<(B * (IN_DIM / 64)) / 4, 256, 0, stream>>>(inp, XbitsT);

    // ---- chunked time loop (CH=100 -> single chunk) ----
    for (int t0 = 0; t0 < T_STEPS; t0 += CH) {
        int L = T_STEPS - t0;
        if (L > CH) L = CH;
        int rows = L * B;            // multiple of 256
        int first = (t0 == 0) ? 1 : 0;

        // layer 1
        gemm_i8<IN_DIM><<<dim3(rows / 256, HID / 16), 256, 0, stream>>>(
            XbitsT, t0 * B, Bq1, C);
        lif_scan<<<(B * (HID / 64)) / 4, 256, 0, stream>>>(
            C, v1, S1T, t0 * B, L, first);

        // layer 2
        gemm_i8<HID><<<dim3(rows / 256, HID / 16), 256, 0, stream>>>(
            S1T, t0 * B, Bq2, C);
        lif_scan<<<(B * (HID / 64)) / 4, 256, 0, stream>>>(
            C, v2, S2T, t0 * B, L, first);

        // output layer
        gemm_out<<<rows / 64, 256, 0, stream>>>(S2T, t0 * B, Who64, C3);
        lif_out<<<(B * OUT_DIM + 255) / 256, 256, 0, stream>>>(
            C3, vo, cnts, out, L, first);
    }
}

// Round 3
// 998.973 us; speedup vs baseline: 1.9961x; 1.9961x over previous
//
#include <hip/hip_runtime.h>
#include <hip/hip_bf16.h>

// SNN: B=256, IN=1024, HID=2048, OUT=10, T=100, decay=0.9, thr=1.0, reset=0.
// Layer-pipelined: GEMM1(all t) -> LIF scan -> GEMM2(all t) -> scan -> GEMM3 -> scan.
// Hidden GEMMs: i8 Ozaki split, 4 digit planes of round(w*2^31) (exact split;
// i32 MFMA accumulation exact).
// Round-17 (vs r16 REGRESSION, vs r15 baseline):
//  - REVERT global geometry to r15 (proven FETCH 113MB / WRITE 344MB):
//    block 128 rows x 32 cols, wave 32x32, 8KB B regions, 32-col C strips.
//    (r16's 16-col strips caused partial-line RMW: WRITE 2GB, fetch 728MB.)
//  - NEW: pair-of-K-steps per barrier window: 32 MFMAs + 16 ds_reads between
//    barriers (was 16+8), 6-slot LDS ring (48KB) staged TWO pairs ahead,
//    "s_waitcnt vmcnt(8); s_barrier" per pair (current pair's 8 VMEM in
//    flight). 3 blocks/CU (LDS-bound); MFMA demand/SIMD/pair ~1958cyc now
//    exceeds LDS-pipe demand -> phases overlap across 3 independent blocks.
//  - T5: s_setprio(1) around each MFMA cluster.
//  - KEPT from r16: fp32 C (single chunk CH=100), lif prefetch, gemm_out
//    4-way k-split, float4 bitpack. cvt_w_i8 reverted to 8KB-region swizzle.

#define B 256
#define IN_DIM 1024
#define HID 2048
#define OUT_DIM 10
#define T_STEPS 100
#define NCH 4
#define RT (T_STEPS * B)   // 25600 global rows

typedef unsigned long long ull;
typedef int v4i __attribute__((ext_vector_type(4)));

// ---- weight fp32 -> 4 signed base-256 digit planes of round(w*2^31),
// swizzled to MFMA fragment order: region per (nb32, wb) = 8192 B, fragment
// (c,ct) at (c*2+ct)*1024, byte lane*16+jj, lane=lk*16+li,
// n = nb32*32 + ct*16 + li, k = wb*64 + lk*16 + jj.
// One thread: 4 consecutive k (same n) -> coalesced W loads, dword stores. ----
template<int K>
__global__ __launch_bounds__(256) void cvt_w_i8(
    const float* __restrict__ W, signed char* __restrict__ Bq)
{
    constexpr int WPR = K / 64;
    size_t id = (size_t)blockIdx.x * 256 + threadIdx.x;
    if (id >= (size_t)(K / 4) * HID) return;
    int n  = (int)(id % HID);
    int kg = (int)(id / HID);
    int k0 = kg * 4;                                  // jj multiple of 4
    signed char dig[4][4];                            // [plane][i]
#pragma unroll
    for (int i = 0; i < 4; ++i) {
        double w = (double)W[(size_t)(k0 + i) * HID + n];
        long long V = __double2ll_rn(w * 2147483648.0);   // w * 2^31
#pragma unroll
        for (int c = 0; c < 3; ++c) {
            int r = (int)(signed char)(V & 0xFF);     // balanced digit [-128,127]
            dig[c][i] = (signed char)r;
            V = (V - r) >> 8;
        }
        dig[3][i] = (signed char)V;                   // |V| <= ~70
    }
    int wb = k0 >> 6, lk = (k0 >> 4) & 3, jj = k0 & 15;
    int nb32 = n >> 5, ct = (n >> 4) & 1, li = n & 15;
    int lane = lk * 16 + li;
    size_t base = ((size_t)nb32 * WPR + wb) * 8192 + (size_t)lane * 16 + jj;
#pragma unroll
    for (int c = 0; c < 4; ++c) {
        int pc = (c < 3) ? (c * 2 + ct) : (6 + ct);
        unsigned pk = (unsigned)(unsigned char)dig[c][0]
                    | ((unsigned)(unsigned char)dig[c][1] << 8)
                    | ((unsigned)(unsigned char)dig[c][2] << 16)
                    | ((unsigned)(unsigned char)dig[c][3] << 24);
        *reinterpret_cast<unsigned*>(Bq + base + (size_t)pc * 1024) = pk;
    }
}

// ---- output weights fp32 -> fp64 (gemm_out stays fp64) ----
__global__ __launch_bounds__(256) void cvt_who(
    const float* __restrict__ who, double* __restrict__ Who64)
{
    int i = blockIdx.x * 256 + threadIdx.x;
    if (i < HID * OUT_DIM) Who64[i] = (double)who[i];
}

// ---- bit-pack input spikes -> TRANSPOSED XbitsT[w][t*256+b] ----
__global__ __launch_bounds__(256) void bitpack_input(
    const float* __restrict__ inp, ull* __restrict__ XbitsT)
{
    int g = blockIdx.x * 4 + (threadIdx.x >> 6);
    int lane = threadIdx.x & 63;
    int b = g >> 4;
    int ig = g & 15;
    int i = ig * 64 + lane;
    const float4* p = (const float4*)(inp + ((size_t)b * IN_DIM + i) * T_STEPS);
    ull* dst = XbitsT + (size_t)ig * RT + b;
#pragma unroll 1
    for (int t4 = 0; t4 < T_STEPS / 4; ++t4) {
        float4 v = p[t4];
        ull m0 = __ballot(v.x > 0.5f);
        ull m1 = __ballot(v.y > 0.5f);
        ull m2 = __ballot(v.z > 0.5f);
        ull m3 = __ballot(v.w > 0.5f);
        if (lane == 0) {
            dst[(size_t)(t4 * 4 + 0) * B] = m0;
            dst[(size_t)(t4 * 4 + 1) * B] = m1;
            dst[(size_t)(t4 * 4 + 2) * B] = m2;
            dst[(size_t)(t4 * 4 + 3) * B] = m3;
        }
    }
}

// ---- i8 Ozaki bit-GEMM: r15 geometry + pair-per-barrier + 6-slot ring ----
// Block: 128 rows x 32 cols, 4 waves (wave = 32 rows x 32 cols).
// Grid: x = rows/128, y = HID/32. row_base = t0*B (global row offset).
// Per PAIR (2 K-steps) per wave: 4 stage + 4 mask loads = 8 VMEM;
// "s_waitcnt vmcnt(8); s_barrier" per pair keeps current pair in flight.
template<int K>
__global__ __launch_bounds__(256, 3) void gemm_i8(
    const ull* __restrict__ bitsT, int row_base,
    const signed char* __restrict__ Bq, float* __restrict__ C)
{
    constexpr int WPR = K / 64;          // 16 (L1) / 32 (L2)
    constexpr int NP  = WPR / 2;         // pairs: 8 / 16  (even)
    __shared__ __align__(16) signed char blds[6][8192];   // 48 KB -> 3 blk/CU

    const int tid = threadIdx.x;
    const int lane = tid & 63;
    const int wv = __builtin_amdgcn_readfirstlane(tid >> 6);
    const int row0 = blockIdx.x * 128;                    // local row base
    const int c0 = blockIdx.y * 32;
    const int li = lane & 15;
    const int lk = lane >> 4;
    const int sh = lk * 16;
    const int r0l = wv * 32;

    const signed char* __restrict__ bsrc = Bq + (size_t)blockIdx.y * WPR * 8192;
    const ull* __restrict__ m0p = bitsT + (row_base + row0 + r0l + li);
    const ull* __restrict__ m1p = m0p + 16;

    // stage B(w) into ring slot: 8 segments of 1 KB, 2 per wave (async to LDS)
    auto stage_b = [&](int w, int slot) {
        const signed char* src = bsrc + (size_t)w * 8192 + lane * 16;
        signed char* db = &blds[0][0] + slot * 8192;
        __builtin_amdgcn_global_load_lds(
            (const __attribute__((address_space(1))) unsigned int*)(src + wv * 1024),
            (__attribute__((address_space(3))) unsigned int*)(db + wv * 1024), 16, 0, 0);
        __builtin_amdgcn_global_load_lds(
            (const __attribute__((address_space(1))) unsigned int*)(src + (wv + 4) * 1024),
            (__attribute__((address_space(3))) unsigned int*)(db + (wv + 4) * 1024), 16, 0, 0);
    };

    // prologue: stage w=0..3 into slots 0..3; mask ring slots u=0..3 hold w=u
    stage_b(0, 0);
    stage_b(1, 1);
    stage_b(2, 2);
    stage_b(3, 3);
    ull r0[4], r1[4];
#pragma unroll
    for (int u = 0; u < 4; ++u) {
        r0[u] = m0p[(size_t)u * RT];
        r1[u] = m1p[(size_t)u * RT];
    }
    __syncthreads();   // full drain once (prologue)

    v4i acc[2][2][NCH];
#pragma unroll
    for (int g = 0; g < 2; ++g)
#pragma unroll
        for (int t = 0; t < 2; ++t)
#pragma unroll
            for (int c = 0; c < NCH; ++c) acc[g][t][c] = (v4i){0, 0, 0, 0};

    // LDS ring slots: pair P consumes slots (2P)%6,(2P+1)%6; stages
    // (2P+4)%6,(2P+5)%6 with data w=2P+4,2P+5. Mask ring: slot u=w&3 holds
    // mask w; refilled with w+4 right after consumption (consumed 2 pairs
    // later; compiler dep-waitcnt guards the register). Tail stages wrap to
    // valid-but-never-consumed w.
    int s0 = 0;                           // slot of w0 = (2P) % 6
#pragma unroll 1
    for (int p2 = 0; p2 < NP; p2 += 2) {  // 2 pairs per outer iter (mask idx const)
#pragma unroll
        for (int pp = 0; pp < 2; ++pp) {
            const int w0 = (p2 + pp) * 2;           // first w of pair
            const int u0 = w0 & 3, u1 = (w0 + 1) & 3;
            int s1 = s0 + 1; if (s1 >= 6) s1 -= 6;
            int t0 = s0 + 4; if (t0 >= 6) t0 -= 6;
            int t1 = s0 + 5; if (t1 >= 6) t1 -= 6;

            // issue next-next pair's stages + mask refills FIRST
            int wn0 = w0 + 4; if (wn0 >= WPR) wn0 -= WPR;   // tail: dummy-valid
            int wn1 = w0 + 5; if (wn1 >= WPR) wn1 -= WPR;
            stage_b(wn0, t0);
            stage_b(wn1, t1);
            ull m00 = r0[u0], m01 = r1[u0];
            ull m10 = r0[u1], m11 = r1[u1];
            r0[u0] = m0p[(size_t)wn0 * RT];
            r1[u0] = m1p[(size_t)wn0 * RT];
            r0[u1] = m0p[(size_t)wn1 * RT];
            r1[u1] = m1p[(size_t)wn1 * RT];

            // ---- K-step A (w0), slot s0 ----
            {
                unsigned sa = (unsigned)(m00 >> sh) & 0xFFFFu;
                unsigned sb = (unsigned)(m01 >> sh) & 0xFFFFu;
                v4i a0, a1;
#pragma unroll
                for (int d = 0; d < 4; ++d) {
                    a0[d] = (int)((((sa >> (4 * d)) & 0xFu) * 0x00204081u) & 0x01010101u);
                    a1[d] = (int)((((sb >> (4 * d)) & 0xFu) * 0x00204081u) & 0x01010101u);
                }
                const signed char* bb = &blds[0][0] + s0 * 8192 + lane * 16;
                __builtin_amdgcn_s_setprio(1);
#pragma unroll
                for (int c = 0; c < NCH; ++c) {
#pragma unroll
                    for (int t = 0; t < 2; ++t) {
                        v4i b = *(const v4i*)(bb + (c * 2 + t) * 1024);
                        acc[0][t][c] = __builtin_amdgcn_mfma_i32_16x16x64_i8(a0, b, acc[0][t][c], 0, 0, 0);
                        acc[1][t][c] = __builtin_amdgcn_mfma_i32_16x16x64_i8(a1, b, acc[1][t][c], 0, 0, 0);
                    }
                }
                __builtin_amdgcn_s_setprio(0);
            }
            // ---- K-step B (w0+1), slot s1 ----
            {
                unsigned sa = (unsigned)(m10 >> sh) & 0xFFFFu;
                unsigned sb = (unsigned)(m11 >> sh) & 0xFFFFu;
                v4i a0, a1;
#pragma unroll
                for (int d = 0; d < 4; ++d) {
                    a0[d] = (int)((((sa >> (4 * d)) & 0xFu) * 0x00204081u) & 0x01010101u);
                    a1[d] = (int)((((sb >> (4 * d)) & 0xFu) * 0x00204081u) & 0x01010101u);
                }
                const signed char* bb = &blds[0][0] + s1 * 8192 + lane * 16;
                __builtin_amdgcn_s_setprio(1);
#pragma unroll
                for (int c = 0; c < NCH; ++c) {
#pragma unroll
                    for (int t = 0; t < 2; ++t) {
                        v4i b = *(const v4i*)(bb + (c * 2 + t) * 1024);
                        acc[0][t][c] = __builtin_amdgcn_mfma_i32_16x16x64_i8(a0, b, acc[0][t][c], 0, 0, 0);
                        acc[1][t][c] = __builtin_amdgcn_mfma_i32_16x16x64_i8(a1, b, acc[1][t][c], 0, 0, 0);
                    }
                }
                __builtin_amdgcn_s_setprio(0);
            }

            // drain previous pair's loads; current pair's 8 stay in flight
            __asm__ __volatile__("s_waitcnt vmcnt(8)\n\ts_barrier" ::: "memory");
            s0 += 2; if (s0 >= 6) s0 -= 6;
        }
    }

    // exact recombination: V = (((S3<<8)+S2)<<8+S1)<<8+S0; |V| < 2^43.
#pragma unroll
    for (int g = 0; g < 2; ++g) {
#pragma unroll
        for (int t = 0; t < 2; ++t) {
#pragma unroll
            for (int r = 0; r < 4; ++r) {
                long long V = (long long)acc[g][t][3][r];
                V = (V << 8) + (long long)acc[g][t][2][r];
                V = (V << 8) + (long long)acc[g][t][1][r];
                V = (V << 8) + (long long)acc[g][t][0][r];
                C[(size_t)(row0 + r0l + g * 16 + lk * 4 + r) * HID + c0 + t * 16 + li] =
                    (float)((double)V * 0x1p-31);
            }
        }
    }
}

// ---- output bit-GEMM: 10 columns, fp64; 4-way k-split + LDS reduce ----
__global__ __launch_bounds__(256) void gemm_out(
    const ull* __restrict__ bitsT, int row_base,
    const double* __restrict__ W, double* __restrict__ C3)
{
    __shared__ double part[3][64][OUT_DIM];   // 15.4 KB
    const int lane = threadIdx.x & 63;
    const int sl = threadIdx.x >> 6;          // k-slice 0..3
    const int row = blockIdx.x * 64 + lane;

    double acc[OUT_DIM];
#pragma unroll
    for (int j = 0; j < OUT_DIM; ++j) acc[j] = 0.0;

    for (int w = sl * 8; w < sl * 8 + 8; ++w) {
        ull m = bitsT[(size_t)w * RT + row_base + row];
        const double* __restrict__ wk = W + (size_t)(w * 64) * OUT_DIM;
#pragma unroll 4
        for (int kk = 0; kk < 64; ++kk) {
            double bd = (double)(unsigned int)(m & 1ull);
            m >>= 1;
#pragma unroll
            for (int j = 0; j < OUT_DIM; ++j)
                acc[j] = fma(bd, wk[j], acc[j]);
            wk += OUT_DIM;
        }
    }
    if (sl) {
#pragma unroll
        for (int j = 0; j < OUT_DIM; ++j) part[sl - 1][lane][j] = acc[j];
    }
    __syncthreads();
    if (sl == 0) {
        double* __restrict__ crow = C3 + (size_t)row * OUT_DIM;
#pragma unroll
        for (int j = 0; j < OUT_DIM; ++j)
            crow[j] = acc[j] + part[0][lane][j] + part[1][lane][j] + part[2][lane][j];
    }
}

// ---- LIF scan for a hidden layer; 4-deep load prefetch ----
__global__ __launch_bounds__(256) void lif_scan(
    const float* __restrict__ C, double* __restrict__ vstate,
    ull* __restrict__ SbitsT, int row_base, int Tl, int first)
{
    int g = blockIdx.x * 4 + (threadIdx.x >> 6);
    int lane = threadIdx.x & 63;
    int b = g >> 5;
    int ng = g & 31;
    int n = ng * 64 + lane;
    const float* __restrict__ Cp = C + (size_t)b * HID + n;
    ull* __restrict__ Sp = SbitsT + (size_t)ng * RT + row_base + b;
    double v = first ? 0.0 : vstate[(size_t)b * HID + n];
    int tl = 0;
    for (; tl + 4 <= Tl; tl += 4) {
        float c0 = Cp[(size_t)(tl + 0) * (B * HID)];
        float c1 = Cp[(size_t)(tl + 1) * (B * HID)];
        float c2 = Cp[(size_t)(tl + 2) * (B * HID)];
        float c3 = Cp[(size_t)(tl + 3) * (B * HID)];
#pragma unroll
        for (int i = 0; i < 4; ++i) {
            float cc = (i == 0) ? c0 : (i == 1) ? c1 : (i == 2) ? c2 : c3;
            v = v * 0.9 + (double)cc;
            bool s = (v >= 1.0);
            if (s) v = 0.0;
            ull mask = __ballot(s);
            if (lane == 0) Sp[(size_t)(tl + i) * B] = mask;
        }
    }
    for (; tl < Tl; ++tl) {
        double c = (double)Cp[(size_t)tl * (B * HID)];
        v = v * 0.9 + c;
        bool s = (v >= 1.0);
        if (s) v = 0.0;
        ull mask = __ballot(s);
        if (lane == 0) Sp[(size_t)tl * B] = mask;
    }
    vstate[(size_t)b * HID + n] = v;
}

// ---- output LIF scan + rate accumulation; 4-deep prefetch ----
__global__ __launch_bounds__(256) void lif_out(
    const double* __restrict__ C3, double* __restrict__ vstate,
    int* __restrict__ cnt_state, float* __restrict__ out, int Tl, int first)
{
    int tid = blockIdx.x * 256 + threadIdx.x;
    if (tid >= B * OUT_DIM) return;
    int b = tid / OUT_DIM, o = tid % OUT_DIM;
    const double* __restrict__ Cp = C3 + (size_t)b * OUT_DIM + o;
    double v = first ? 0.0 : vstate[tid];
    int cnt = first ? 0 : cnt_state[tid];
    int tl = 0;
    for (; tl + 4 <= Tl; tl += 4) {
        double c0 = Cp[(size_t)(tl + 0) * (B * OUT_DIM)];
        double c1 = Cp[(size_t)(tl + 1) * (B * OUT_DIM)];
        double c2 = Cp[(size_t)(tl + 2) * (B * OUT_DIM)];
        double c3 = Cp[(size_t)(tl + 3) * (B * OUT_DIM)];
#pragma unroll
        for (int i = 0; i < 4; ++i) {
            double cc = (i == 0) ? c0 : (i == 1) ? c1 : (i == 2) ? c2 : c3;
            v = v * 0.9 + cc;
            if (v >= 1.0) { cnt++; v = 0.0; }
        }
    }
    for (; tl < Tl; ++tl) {
        double c = Cp[(size_t)tl * (B * OUT_DIM)];
        v = v * 0.9 + c;
        if (v >= 1.0) { cnt++; v = 0.0; }
    }
    vstate[tid] = v;
    cnt_state[tid] = cnt;
    out[tid] = (float)((double)cnt / (double)T_STEPS);
}

extern "C" void kernel_launch(void* const* d_in, const int* in_sizes, int n_in,
                              void* d_out, int out_size, void* d_ws, size_t ws_size,
                              hipStream_t stream) {
    const float* inp = (const float*)d_in[0];   // [256,1024,100]
    const float* wih = (const float*)d_in[1];   // [1024,2048]
    const float* whh = (const float*)d_in[2];   // [1,2048,2048]
    const float* who = (const float*)d_in[3];   // [2048,10]
    float* out = (float*)d_out;                 // [256,10]

    // ---- workspace layout ----
    unsigned char* p = (unsigned char*)d_ws;
    auto alloc = [&](size_t sz) -> void* {
        void* r = (void*)p;
        p += (sz + 255) & ~(size_t)255;
        return r;
    };
    signed char* Bq1 = (signed char*)alloc((size_t)NCH * HID * IN_DIM + 4096); // 8.4 MB
    signed char* Bq2 = (signed char*)alloc((size_t)NCH * HID * HID + 4096);    // 16.8 MB
    double* Who64 = (double*)alloc((size_t)HID * OUT_DIM * 8);
    ull* XbitsT = (ull*)alloc((size_t)16 * RT * 8);        // 3.3 MB
    ull* S1T    = (ull*)alloc((size_t)32 * RT * 8);        // 6.6 MB
    ull* S2T    = (ull*)alloc((size_t)32 * RT * 8);        // 6.6 MB
    double* v1 = (double*)alloc((size_t)B * HID * 8);
    double* v2 = (double*)alloc((size_t)B * HID * 8);
    double* vo = (double*)alloc((size_t)B * OUT_DIM * 8);
    int* cnts  = (int*)alloc((size_t)B * OUT_DIM * 4);

    size_t used = (size_t)(p - (unsigned char*)d_ws);
    size_t remain = (ws_size > used) ? (ws_size - used) : 0;
    size_t per_t = (size_t)B * HID * 4 + (size_t)B * OUT_DIM * 8 + 1024;
    int CH = (int)(remain / per_t);
    if (CH > T_STEPS) CH = T_STEPS;
    if (CH < 1) CH = 1;
    double* C3 = (double*)alloc((size_t)CH * B * OUT_DIM * 8);
    float* C   = (float*)alloc((size_t)CH * B * HID * 4);

    // ---- one-time prep ----
    cvt_w_i8<IN_DIM><<<((IN_DIM / 4) * HID + 255) / 256, 256, 0, stream>>>(wih, Bq1);
    cvt_w_i8<HID><<<((HID / 4) * HID + 255) / 256, 256, 0, stream>>>(whh, Bq2);
    cvt_who<<<(HID * OUT_DIM + 255) / 256, 256, 0, stream>>>(who, Who64);
    bitpack_input<<<(B * (IN_DIM / 64)) / 4, 256, 0, stream>>>(inp, XbitsT);

    // ---- chunked time loop (CH=100 -> single chunk) ----
    for (int t0 = 0; t0 < T_STEPS; t0 += CH) {
        int L = T_STEPS - t0;
        if (L > CH) L = CH;
        int rows = L * B;            // multiple of 256
        int first = (t0 == 0) ? 1 : 0;

        // layer 1
        gemm_i8<IN_DIM><<<dim3(rows / 128, HID / 32), 256, 0, stream>>>(
            XbitsT, t0 * B, Bq1, C);
        lif_scan<<<(B * (HID / 64)) / 4, 256, 0, stream>>>(
            C, v1, S1T, t0 * B, L, first);

        // layer 2
        gemm_i8<HID><<<dim3(rows / 128, HID / 32), 256, 0, stream>>>(
            S1T, t0 * B, Bq2, C);
        lif_scan<<<(B * (HID / 64)) / 4, 256, 0, stream>>>(
            C, v2, S2T, t0 * B, L, first);

        // output layer
        gemm_out<<<rows / 64, 256, 0, stream>>>(S2T, t0 * B, Who64, C3);
        lif_out<<<(B * OUT_DIM + 255) / 256, 256, 0, stream>>>(
            C3, vo, cnts, out, L, first);
    }
}